// Round 1
// baseline (293.783 us; speedup 1.0000x reference)
//
#include <hip/hip_runtime.h>
#include <hip/hip_fp16.h>

// CTC loss forward, sum over batch — FUSED single-kernel version, NO WORKSPACE.
//
// Rationale (rocprof): the timed region was dominated by the harness's
// per-iteration 512 MB workspace poison fills (~74 us each, top-5 dispatches
// all fillBufferAligned). Using d_ws at all costs ~150 us/iteration. This
// version never touches d_ws:
//   - one 1024-thread block per batch element b (16 waves)
//   - waves 1..15 (producers): gather logp[t,b,ext[l]], exponentiate
//     (p' = exp(lp + OFF), fp16-safe), pack fp16x4, write into a
//     double-buffered LDS ring of CHUNK=120 rows x 408 B
//   - wave 0 (consumer): serial alpha recurrence over LDS rows, lane owns
//     4 trellis positions, cross-lane via DPP wave_shr:1, exact pow2
//     rescale every 16 steps (esum tracks the log scale)
//   - one __syncthreads per chunk; produce(c+1) overlaps consume(c)
// Numerics identical to the previous verified 2-kernel version (same fp16
// staging values, same rescale points t%16==0, t=0 init through fp16).

constexpr int T = 1000, B = 32, C = 1000, S = 100;
constexpr int L = 2 * S + 1;        // 201
constexpr int RS = 204;             // padded row stride (halves) -> 408 B, 8B-aligned
constexpr int CHUNK = 120;          // rows per LDS chunk
constexpr int NPROD = 15;           // producer waves (block = 16 waves)
constexpr int RPP = CHUNK / NPROD;  // rows per producer wave per chunk = 8
constexpr float OFF = 7.0f;         // emission log-offset
constexpr float LOG2E = 1.4426950408889634f;
constexpr float LN2 = 0.6931471805599453f;

// DPP wave_shr:1 — lane i reads lane i-1; lane 0 gets 0 (bound_ctrl).
__device__ __forceinline__ float dpp_shr1(float x) {
    return __int_as_float(
        __builtin_amdgcn_update_dpp(0, __float_as_int(x), 0x138, 0xF, 0xF, true));
}

// Wave-wide max of NONNEGATIVE values via gfx9 DPP ladder; result uniform.
__device__ __forceinline__ float wave_max_nonneg(float x) {
#define DPP_MAX(ctrl)                                                        \
    x = fmaxf(x, __int_as_float(__builtin_amdgcn_update_dpp(                 \
                     0, __float_as_int(x), (ctrl), 0xF, 0xF, true)))
    DPP_MAX(0x111);  // row_shr:1
    DPP_MAX(0x112);  // row_shr:2
    DPP_MAX(0x114);  // row_shr:4
    DPP_MAX(0x118);  // row_shr:8  -> lane15/31/47/63 hold 16-lane maxes
    DPP_MAX(0x142);  // row_bcast15 -> lane31/63 hold 32-lane maxes
    DPP_MAX(0x143);  // row_bcast31 -> lane63 holds wave max
#undef DPP_MAX
    return __int_as_float(__builtin_amdgcn_readlane(__float_as_int(x), 63));
}

// 4 packed halves (as uint2, 8B) -> 4 floats
__device__ __forceinline__ void h4_to_f(const uint2 q, float& x, float& y,
                                        float& z, float& w) {
    const __half2 lo = *reinterpret_cast<const __half2*>(&q.x);
    const __half2 hi = *reinterpret_cast<const __half2*>(&q.y);
    const float2 f01 = __half22float2(lo);
    const float2 f23 = __half22float2(hi);
    x = f01.x; y = f01.y; z = f23.x; w = f23.y;
}

__global__ void __launch_bounds__(1024) ctc_fused_kernel(
        const float* __restrict__ logp, const int* __restrict__ targets,
        const int* __restrict__ input_lens, const int* __restrict__ target_lens,
        float* __restrict__ out) {
    __shared__ __half lds[2][CHUNK][RS];  // 2 * 120 * 204 * 2 B = 97,920 B

    const int b = blockIdx.x;
    const int wave = threadIdx.x >> 6;
    const int lane = threadIdx.x & 63;
    const int Tb = input_lens[b];
    const int tl = target_lens[b];
    // lanes 0..50 own trellis positions 4*lane..4*lane+3; 51..63 dead (clamped)
    const int col = (lane <= 50) ? 4 * lane : 200;

    const int steps = Tb - 1;                       // recurrence steps t=1..Tb-1
    const int NC = (steps + CHUNK - 1) / CHUNK;     // chunks (may be 0)

    if (wave > 0) {
        // ------------------------- producers -------------------------
        const int p = wave - 1;  // 0..14
        int cc[4];
        float pm[4];
#pragma unroll
        for (int i = 0; i < 4; ++i) {
            const int l = col + i;
            const bool real = (lane <= 50) && (l < L);
            pm[i] = real ? 1.f : 0.f;
            cc[i] = real ? ((l & 1) ? targets[b * S + (l >> 1)] : 0) : 0;
        }
        auto produce = [&](int c, int bi) {
            const int t0 = 1 + c * CHUNK;
#pragma unroll 2
            for (int rr = 0; rr < RPP; ++rr) {
                const int r = p + rr * NPROD;   // < CHUNK by construction
                const int t = t0 + r;
                if (t >= Tb) break;             // wave-uniform
                const float* row = logp + ((size_t)t * B + b) * C;
                const float p0 = pm[0] * exp2f((row[cc[0]] + OFF) * LOG2E);
                const float p1 = pm[1] * exp2f((row[cc[1]] + OFF) * LOG2E);
                const float p2 = pm[2] * exp2f((row[cc[2]] + OFF) * LOG2E);
                const float p3 = pm[3] * exp2f((row[cc[3]] + OFF) * LOG2E);
                if (lane <= 50) {
                    const __half2 lo = __floats2half2_rn(p0, p1);
                    const __half2 hi = __floats2half2_rn(p2, p3);
                    uint2 q;
                    q.x = *reinterpret_cast<const unsigned int*>(&lo);
                    q.y = *reinterpret_cast<const unsigned int*>(&hi);
                    // lane 50 covers cols 200..203; pads (201..203) are 0 ->
                    // keeps the dead-lane invariant for the consumer.
                    *reinterpret_cast<uint2*>(&lds[bi][r][col]) = q;
                }
            }
        };
        if (NC > 0) produce(0, 0);
        __syncthreads();
        for (int c = 0; c < NC; ++c) {
            if (c + 1 < NC) produce(c + 1, (c + 1) & 1);
            __syncthreads();
        }
        return;  // no further barriers anywhere -> safe to exit
    }

    // ------------------------- consumer (wave 0) -------------------------
    // Skip-transition masks: only odd positions (col+1, col+3) can skip.
    float m1 = 0.f, m3 = 0.f;
    if (lane <= 50) {
        const int l1 = col + 1;
        if (l1 >= 3 && l1 < L) {
            const int s = (l1 - 1) >> 1;
            if (targets[b * S + s] != targets[b * S + s - 1]) m1 = 1.f;
        }
        const int l3 = col + 3;
        if (l3 >= 3 && l3 < L) {
            const int s = (l3 - 1) >> 1;
            if (targets[b * S + s] != targets[b * S + s - 1]) m3 = 1.f;
        }
    }

    // init at t=0: alpha[0] = p(blank), alpha[1] = p(tgt0), rest 0.
    // Round through fp16 so values match the previous staged version exactly.
    float a0 = 0.f, a1 = 0.f, a2 = 0.f, a3 = 0.f;
    if (lane == 0) {
        const float* r0 = logp + (size_t)b * C;  // t = 0 row
        a0 = __half2float(__float2half(exp2f((r0[0] + OFF) * LOG2E)));
        a1 = __half2float(__float2half(exp2f((r0[targets[b * S]] + OFF) * LOG2E)));
    }
    int esum = 0;

    // Dead-lane invariant: lane 50's cols 201..203 are staged 0, so its
    // a1..a3 stay 0; lanes 51+ receive zeros via DPP and multiply by their
    // (duplicated) emissions against zero sums -> stay 0. No masking needed.
#define CTC_STEP(Q_)                                  \
    do {                                              \
        float px, py, pz, pwv;                        \
        h4_to_f((Q_), px, py, pz, pwv);               \
        const float am1 = dpp_shr1(a3);               \
        const float s01 = a0 + a1;                    \
        const float s23 = a2 + a3;                    \
        const float n0 = (a0 + am1) * px;             \
        const float n1 = fmaf(am1, m1, s01) * py;     \
        const float n2 = (a1 + a2) * pz;              \
        const float n3 = fmaf(a1, m3, s23) * pwv;     \
        a0 = n0; a1 = n1; a2 = n2; a3 = n3;           \
    } while (0)

#define CTC_RESCALE()                                                          \
    do {                                                                       \
        const float mx = wave_max_nonneg(fmaxf(fmaxf(a0, a1), fmaxf(a2, a3))); \
        const unsigned bits = __float_as_uint(mx);                             \
        if (bits != 0u) {                                                      \
            const int e = (int)((bits >> 23) & 0xFFu) - 127;                   \
            const float sc = __uint_as_float((unsigned)(127 - e) << 23);       \
            a0 *= sc; a1 *= sc; a2 *= sc; a3 *= sc;                            \
            esum += e;                                                         \
        }                                                                      \
    } while (0)

    __syncthreads();  // chunk 0 staged
    for (int c = 0; c < NC; ++c) {
        const int bi = c & 1;
        const int t0 = 1 + c * CHUNK;
        const int rend = min(CHUNK, Tb - t0);
#pragma unroll 4
        for (int r = 0; r < rend; ++r) {
            const uint2 q = *reinterpret_cast<const uint2*>(&lds[bi][r][col]);
            CTC_STEP(q);
            // same rescale points as the verified version: after step t%16==0
            if (((t0 + r) & 15) == 0) CTC_RESCALE();
        }
        __syncthreads();  // consume(c) done; produce(c+1) done
    }
#undef CTC_STEP
#undef CTC_RESCALE

    // final: sum alpha at positions 2*tl and 2*tl-1
    const int e1 = 2 * tl, e2 = 2 * tl - 1;
    float contrib = 0.f;
    if (lane <= 50) {
        if (col + 0 == e1 || col + 0 == e2) contrib += a0;
        if (col + 1 == e1 || col + 1 == e2) contrib += a1;
        if (col + 2 == e1 || col + 2 == e2) contrib += a2;
        if (col + 3 == e1 || col + 3 == e2) contrib += a3;
    }
#pragma unroll
    for (int off = 32; off; off >>= 1) contrib += __shfl_xor(contrib, off);

    if (lane == 0) {
        const float logalpha = logf(contrib) + (float)esum * LN2 - OFF * (float)Tb;
        float loss = -logalpha;
        if (!(loss < 0.5e30f)) loss = 0.f;  // zero_infinity (catches NaN/inf too)
        atomicAdd(out, loss);
    }
}

extern "C" void kernel_launch(void* const* d_in, const int* in_sizes, int n_in,
                              void* d_out, int out_size, void* d_ws, size_t ws_size,
                              hipStream_t stream) {
    (void)d_ws; (void)ws_size; (void)in_sizes; (void)n_in; (void)out_size;
    const float* logp = (const float*)d_in[0];
    const int* targets = (const int*)d_in[1];
    const int* input_lens = (const int*)d_in[2];
    const int* target_lens = (const int*)d_in[3];
    float* out = (float*)d_out;

    hipMemsetAsync(d_out, 0, sizeof(float), stream);
    ctc_fused_kernel<<<B, 1024, 0, stream>>>(logp, targets, input_lens,
                                             target_lens, out);
}

// Round 2
// 234.874 us; speedup vs baseline: 1.2508x; 1.2508x over previous
//
#include <hip/hip_runtime.h>
#include <hip/hip_fp16.h>

// CTC loss forward, sum over batch. Two kernels, fp32 workspace staging.
//
// Round-1 lesson (rocprof): the 512 MB workspace poison fills (~2x74 us) are
// STRUCTURAL — they run whether or not the kernel touches d_ws. So ws use is
// free. The fused 32-block version was gather-latency-bound (397 GB/s, 5%
// occupancy). Restore the split:
//   Kernel A (stage): 32000 waves gather only the needed columns
//     (blank + targets ~= 102 of 1000), exponentiate with OFF, store fp32
//     rows of 204 floats to ws. Fetch ~62 MB (proven by round-1 FETCH_SIZE),
//     fully occupancy-hidden.
//   Kernel B (recurrence): one wave per batch element; lane owns 4 trellis
//     positions; DPP wave_shr:1 cross-lane; float4 emission ring PFD=32 deep
//     (fp32 staging removes 4 cvt/step from the serial chain); exact pow2
//     rescale every 16 steps (esum tracks log scale; mathematically lossless).

constexpr int T = 1000, B = 32, C = 1000, S = 100;
constexpr int L = 2 * S + 1;      // 201
constexpr int RS = 204;           // row stride (floats) = 816 B, 16B-aligned
constexpr int PFD = 32;           // prefetch depth
constexpr int RROWS = T + PFD;    // pad rows so the prefetch stays in-bounds
constexpr float OFF = 7.0f;       // emission log-offset
constexpr float LOG2E = 1.4426950408889634f;
constexpr float LN2 = 0.6931471805599453f;

// DPP wave_shr:1 — lane i reads lane i-1; lane 0 gets 0 (bound_ctrl).
__device__ __forceinline__ float dpp_shr1(float x) {
    return __int_as_float(
        __builtin_amdgcn_update_dpp(0, __float_as_int(x), 0x138, 0xF, 0xF, true));
}

// Wave-wide max of NONNEGATIVE values via gfx9 DPP ladder; result uniform.
__device__ __forceinline__ float wave_max_nonneg(float x) {
#define DPP_MAX(ctrl)                                                        \
    x = fmaxf(x, __int_as_float(__builtin_amdgcn_update_dpp(                 \
                     0, __float_as_int(x), (ctrl), 0xF, 0xF, true)))
    DPP_MAX(0x111);  // row_shr:1
    DPP_MAX(0x112);  // row_shr:2
    DPP_MAX(0x114);  // row_shr:4
    DPP_MAX(0x118);  // row_shr:8  -> lane15/31/47/63 hold 16-lane maxes
    DPP_MAX(0x142);  // row_bcast15 -> lane31/63 hold 32-lane maxes
    DPP_MAX(0x143);  // row_bcast31 -> lane63 holds wave max
#undef DPP_MAX
    return __int_as_float(__builtin_amdgcn_readlane(__float_as_int(x), 63));
}

// ---------------- Kernel A: gather + exponentiate staging ----------------
// grid (T/4, B), 256 threads (4 waves); wave w stages row t = 4*bx + w.
__global__ void __launch_bounds__(256) stage_kernel(
        const float* __restrict__ logp, const int* __restrict__ targets,
        float* __restrict__ ws) {
    const int t = blockIdx.x * 4 + (threadIdx.x >> 6);
    const int b = blockIdx.y;
    const int lane = threadIdx.x & 63;
    if (lane > 50) return;
    const int col = 4 * lane;  // 0..200
    const float* row = logp + ((size_t)t * B + b) * C;

    // even positions are blanks (class 0) -> same value for the whole row
    const float pb = exp2f((row[0] + OFF) * LOG2E);
    float p1 = 0.f, p3 = 0.f;
    const int l1 = col + 1;
    if (l1 < L) p1 = exp2f((row[targets[b * S + (l1 >> 1)]] + OFF) * LOG2E);
    const int l3 = col + 3;
    if (l3 < L) p3 = exp2f((row[targets[b * S + (l3 >> 1)]] + OFF) * LOG2E);

    float4 v;
    v.x = pb;                          // col   (even, < L always: col<=200)
    v.y = p1;                          // col+1 (0 for lane 50 pad)
    v.z = (col + 2 < L) ? pb : 0.f;    // col+2 (0 for lane 50 pad)
    v.w = p3;                          // col+3 (0 for lane 50 pad)
    *reinterpret_cast<float4*>(ws + ((size_t)b * RROWS + t) * RS + col) = v;
}

// ---------------- Kernel B: recurrence ----------------
__global__ void __launch_bounds__(64, 1) ctc_kernel(
        const float* __restrict__ ws, const int* __restrict__ targets,
        const int* __restrict__ input_lens, const int* __restrict__ target_lens,
        float* __restrict__ out) {
    const int b = blockIdx.x;
    const int lane = threadIdx.x;
    // lanes 0..50 own positions 4*lane..4*lane+3; lanes 51..63 dead (clamped)
    const int col = (lane <= 50) ? 4 * lane : 200;
    const int Tb = input_lens[b];
    const int tl = target_lens[b];
    const float* pw = ws + (size_t)b * RROWS * RS;

    // Skip masks: only odd positions (col+1, col+3) can skip.
    float m1 = 0.f, m3 = 0.f;
    if (lane <= 50) {
        const int l1 = col + 1;
        if (l1 >= 3 && l1 < L) {
            const int s = (l1 - 1) >> 1;
            if (targets[b * S + s] != targets[b * S + s - 1]) m1 = 1.f;
        }
        const int l3 = col + 3;
        if (l3 >= 3 && l3 < L) {
            const int s = (l3 - 1) >> 1;
            if (targets[b * S + s] != targets[b * S + s - 1]) m3 = 1.f;
        }
    }

    // init at t=0: alpha[0] = p(blank), alpha[1] = p(tgt0), rest 0
    float a0 = 0.f, a1 = 0.f, a2 = 0.f, a3 = 0.f;
    {
        const float4 q0 = *reinterpret_cast<const float4*>(pw + col);
        if (lane == 0) { a0 = q0.x; a1 = q0.y; }
    }
    int esum = 0;

    // Dead-lane invariant: lane 50's cols 201..203 staged 0 -> its a1..a3
    // stay 0; lanes 51+ receive zeros via DPP and stay 0. Lane 0 gets 0 via
    // bound_ctrl. No masking needed in the step.
#define CTC_STEP(Q_)                                  \
    do {                                              \
        const float am1 = dpp_shr1(a3);               \
        const float s01 = a0 + a1;                    \
        const float s23 = a2 + a3;                    \
        const float n0 = (a0 + am1) * (Q_).x;         \
        const float n1 = fmaf(am1, m1, s01) * (Q_).y; \
        const float n2 = (a1 + a2) * (Q_).z;          \
        const float n3 = fmaf(a1, m3, s23) * (Q_).w;  \
        a0 = n0; a1 = n1; a2 = n2; a3 = n3;           \
    } while (0)

#define CTC_RESCALE()                                                          \
    do {                                                                       \
        const float mx = wave_max_nonneg(fmaxf(fmaxf(a0, a1), fmaxf(a2, a3))); \
        const unsigned bits = __float_as_uint(mx);                             \
        if (bits != 0u) {                                                      \
            const int e = (int)((bits >> 23) & 0xFFu) - 127;                   \
            const float sc = __uint_as_float((unsigned)(127 - e) << 23);       \
            a0 *= sc; a1 *= sc; a2 *= sc; a3 *= sc;                            \
            esum += e;                                                         \
        }                                                                      \
    } while (0)

    // prefetch ring: P[i] holds the emission row (float4) for step t+i
    float4 P[PFD];
    {
        const float* pf0 = pw + (size_t)RS + col;
#pragma unroll
        for (int i = 0; i < PFD; ++i)
            P[i] = *reinterpret_cast<const float4*>(pf0 + (size_t)i * RS);
    }
    const float* pf = pw + (size_t)(PFD + 1) * RS + col;  // next row to fetch

    int t = 1;
    while (t + PFD <= Tb) {
#pragma unroll
        for (int i = 0; i < PFD; ++i) {
            const float4 q = P[i];
            P[i] = *reinterpret_cast<const float4*>(pf);  // PFD steps ahead
            pf += RS;
            CTC_STEP(q);
            if (i == 15) CTC_RESCALE();  // keep 16-step rescale cadence
        }
        CTC_RESCALE();
        t += PFD;
    }
    // tail (< PFD steps)
    {
        const int rem = Tb - t;
#pragma unroll
        for (int i = 0; i < PFD; ++i) {
            if (i < rem) {
                const float4 q = P[i];
                CTC_STEP(q);
                if (i == 15) CTC_RESCALE();  // bound any unrescaled run
            }
        }
    }
#undef CTC_STEP

    // final: sum alpha at positions 2*tl and 2*tl-1
    const int e1 = 2 * tl, e2 = 2 * tl - 1;
    float contrib = 0.f;
    if (lane <= 50) {
        if (col + 0 == e1 || col + 0 == e2) contrib += a0;
        if (col + 1 == e1 || col + 1 == e2) contrib += a1;
        if (col + 2 == e1 || col + 2 == e2) contrib += a2;
        if (col + 3 == e1 || col + 3 == e2) contrib += a3;
    }
#pragma unroll
    for (int off = 32; off; off >>= 1) contrib += __shfl_xor(contrib, off);

    if (lane == 0) {
        const float logalpha = logf(contrib) + (float)esum * LN2 - OFF * (float)Tb;
        float loss = -logalpha;
        if (!(loss < 0.5e30f)) loss = 0.f;  // zero_infinity (catches NaN/inf)
        atomicAdd(out, loss);
    }
}

// ---------------- Fallback: direct gather (if ws too small) ----------------
__global__ void __launch_bounds__(64, 1) ctc_direct_kernel(
        const float* __restrict__ logp, const int* __restrict__ targets,
        const int* __restrict__ input_lens, const int* __restrict__ target_lens,
        float* __restrict__ out) {
    const int b = blockIdx.x;
    const int lane = threadIdx.x;
    const int col = (lane <= 50) ? 4 * lane : 200;
    const int Tb = input_lens[b];
    const int tl = target_lens[b];

    int cc[4]; float mm[4], pm[4];
#pragma unroll
    for (int i = 0; i < 4; ++i) {
        const int l = col + i;
        const bool real = (lane <= 50) && (l < L);
        pm[i] = real ? 1.f : 0.f;
        cc[i] = real ? ((l & 1) ? targets[b * S + (l >> 1)] : 0) : 0;
        float mk = 0.f;
        if (real && (l & 1) && l >= 3) {
            const int s = (l - 1) >> 1;
            if (targets[b * S + s] != targets[b * S + s - 1]) mk = 1.f;
        }
        mm[i] = mk;
    }
    const float m1 = mm[1], m3 = mm[3];

    float a0 = 0.f, a1 = 0.f, a2 = 0.f, a3 = 0.f;
    {
        const float* rowp = logp + (size_t)b * C;
        const float p0 = pm[0] * exp2f((rowp[cc[0]] + OFF) * LOG2E);
        const float p1 = pm[1] * exp2f((rowp[cc[1]] + OFF) * LOG2E);
        if (lane == 0) { a0 = p0; a1 = p1; }
    }
    int esum = 0;

    for (int t = 1; t < Tb; ++t) {
        const float* rowp = logp + ((size_t)t * B + b) * C;
        const float p0 = pm[0] * exp2f((rowp[cc[0]] + OFF) * LOG2E);
        const float p1 = pm[1] * exp2f((rowp[cc[1]] + OFF) * LOG2E);
        const float p2 = pm[2] * exp2f((rowp[cc[2]] + OFF) * LOG2E);
        const float p3 = pm[3] * exp2f((rowp[cc[3]] + OFF) * LOG2E);
        const float am1 = dpp_shr1(a3);
        const float n0 = (a0 + am1) * p0;
        const float n1 = fmaf(am1, m1, a0 + a1) * p1;
        const float n2 = (a1 + a2) * p2;
        const float n3 = fmaf(a1, m3, a2 + a3) * p3;
        a0 = n0; a1 = n1; a2 = n2; a3 = n3;
        if ((t & 15) == 0) {
            const float mx = wave_max_nonneg(fmaxf(fmaxf(a0, a1), fmaxf(a2, a3)));
            const unsigned bits = __float_as_uint(mx);
            if (bits != 0u) {
                const int e = (int)((bits >> 23) & 0xFFu) - 127;
                const float sc = __uint_as_float((unsigned)(127 - e) << 23);
                a0 *= sc; a1 *= sc; a2 *= sc; a3 *= sc;
                esum += e;
            }
        }
    }

    const int e1 = 2 * tl, e2 = 2 * tl - 1;
    float contrib = 0.f;
    if (lane <= 50) {
        if (col + 0 == e1 || col + 0 == e2) contrib += a0;
        if (col + 1 == e1 || col + 1 == e2) contrib += a1;
        if (col + 2 == e1 || col + 2 == e2) contrib += a2;
        if (col + 3 == e1 || col + 3 == e2) contrib += a3;
    }
#pragma unroll
    for (int off = 32; off; off >>= 1) contrib += __shfl_xor(contrib, off);
    if (lane == 0) {
        const float logalpha = logf(contrib) + (float)esum * LN2 - OFF * (float)Tb;
        float loss = -logalpha;
        if (!(loss < 0.5e30f)) loss = 0.f;
        atomicAdd(out, loss);
    }
}

extern "C" void kernel_launch(void* const* d_in, const int* in_sizes, int n_in,
                              void* d_out, int out_size, void* d_ws, size_t ws_size,
                              hipStream_t stream) {
    (void)in_sizes; (void)n_in; (void)out_size;
    const float* logp = (const float*)d_in[0];
    const int* targets = (const int*)d_in[1];
    const int* input_lens = (const int*)d_in[2];
    const int* target_lens = (const int*)d_in[3];
    float* out = (float*)d_out;
    float* ws = (float*)d_ws;

    hipMemsetAsync(d_out, 0, sizeof(float), stream);

    const size_t ws_needed = (size_t)B * RROWS * RS * sizeof(float);
    if (ws_size >= ws_needed) {
        dim3 gA(T / 4, B);
        stage_kernel<<<gA, 256, 0, stream>>>(logp, targets, ws);
        ctc_kernel<<<B, 64, 0, stream>>>(ws, targets, input_lens, target_lens, out);
    } else {
        ctc_direct_kernel<<<B, 64, 0, stream>>>(logp, targets, input_lens,
                                                target_lens, out);
    }
}